// Round 1
// baseline (849.800 us; speedup 1.0000x reference)
//
#include <hip/hip_runtime.h>
#include <math.h>

#define S_ 16384
#define D_ 2048
#define DM_ 64
#define DK_ 384
#define NMEM_ 128
#define EPS_ 1e-5f

// ---------------- Kernel 1: Q = hs @ Wmq^T   (S x D)@(D x 64) -> (S x 64)
// 256 threads, BM=64, BN=64, BK=32, 4x4 outputs/thread
__global__ __launch_bounds__(256) void k_qgemm(const float* __restrict__ hs,
                                               const float* __restrict__ Wmq,
                                               float* __restrict__ Q) {
    __shared__ float As[64][33];
    __shared__ float Bs[32][65];
    const int r0 = blockIdx.x * 64;
    const int tid = threadIdx.x;
    const int tcol = tid & 15, trow = tid >> 4;
    float acc[4][4] = {};
    for (int k0 = 0; k0 < D_; k0 += 32) {
#pragma unroll
        for (int i = 0; i < 8; ++i) {
            int flat = tid + 256 * i;
            int r = flat >> 5, kk = flat & 31;
            As[r][kk] = hs[(size_t)(r0 + r) * D_ + k0 + kk];
        }
#pragma unroll
        for (int i = 0; i < 8; ++i) {
            int flat = tid + 256 * i;
            int c = flat >> 5, kk = flat & 31;
            Bs[kk][c] = Wmq[(size_t)c * D_ + k0 + kk];
        }
        __syncthreads();
#pragma unroll
        for (int kk = 0; kk < 32; ++kk) {
            float a_[4], b_[4];
#pragma unroll
            for (int rr = 0; rr < 4; ++rr) a_[rr] = As[trow * 4 + rr][kk];
#pragma unroll
            for (int cc = 0; cc < 4; ++cc) b_[cc] = Bs[kk][tcol * 4 + cc];
#pragma unroll
            for (int rr = 0; rr < 4; ++rr)
#pragma unroll
                for (int cc = 0; cc < 4; ++cc)
                    acc[rr][cc] += a_[rr] * b_[cc];
        }
        __syncthreads();
    }
#pragma unroll
    for (int rr = 0; rr < 4; ++rr)
#pragma unroll
        for (int cc = 0; cc < 4; ++cc)
            Q[(size_t)(r0 + trow * 4 + rr) * DM_ + tcol * 4 + cc] = acc[rr][cc];
}

// ---------------- Kernel 2: out = (dpfp(Q) @ W_mem)/denom + hs
// 256 threads, BM=32 rows, BN=256 cols, K=384
__global__ __launch_bounds__(256) void k_main(const float* __restrict__ hs,
                                              const float* __restrict__ Q,
                                              const float* __restrict__ Wmem,
                                              const float* __restrict__ z,
                                              float* __restrict__ out) {
    __shared__ float xs[32][128];
    __shared__ float mqs[32][385];
    __shared__ float denomS[32];
    const int r0 = blockIdx.x * 32;
    const int c0 = blockIdx.y * 256;
    const int tid = threadIdx.x;
    // stage x = [relu(q), relu(-q)]
#pragma unroll
    for (int i = 0; i < 8; ++i) {
        int flat = tid + 256 * i;            // 0..2047
        int r = flat >> 6, c = flat & 63;
        float v = Q[(size_t)(r0 + r) * DM_ + c];
        xs[r][c] = fmaxf(v, 0.f);
        xs[r][c + 64] = fmaxf(-v, 0.f);
    }
    __syncthreads();
    // mq tile: mq[m] = x[m&127] * x[(m - (m>>7) - 1) & 127]
    {
        int m = tid & 127;
        int rbase = tid >> 7;                // 0 or 1
#pragma unroll
        for (int g = 0; g < 3; ++g) {
            int idx2 = (m - g - 1) & 127;
            int mm = m + 128 * g;
            for (int rr = 0; rr < 32; rr += 2) {
                int r = rr + rbase;
                mqs[r][mm] = xs[r][m] * xs[r][idx2];
            }
        }
    }
    __syncthreads();
    // denom per row
    {
        int row = tid >> 3, l8 = tid & 7;
        float p = 0.f;
        for (int k = l8; k < DK_; k += 8) p += mqs[row][k] * z[k];
        p += __shfl_down(p, 4, 8);
        p += __shfl_down(p, 2, 8);
        p += __shfl_down(p, 1, 8);
        if (l8 == 0) denomS[row] = p + EPS_;
    }
    __syncthreads();
    const int tc = tid & 31, tr = tid >> 5;  // tr 0..7 -> 4 rows each; tc -> 8 cols strided 32
    float acc[4][8] = {};
#pragma unroll 4
    for (int k = 0; k < DK_; ++k) {
        float a_[4], b_[8];
#pragma unroll
        for (int cc = 0; cc < 8; ++cc) b_[cc] = Wmem[(size_t)k * D_ + c0 + tc + 32 * cc];
#pragma unroll
        for (int rr = 0; rr < 4; ++rr) a_[rr] = mqs[tr * 4 + rr][k];
#pragma unroll
        for (int rr = 0; rr < 4; ++rr)
#pragma unroll
            for (int cc = 0; cc < 8; ++cc)
                acc[rr][cc] += a_[rr] * b_[cc];
    }
#pragma unroll
    for (int rr = 0; rr < 4; ++rr) {
        int row = r0 + tr * 4 + rr;
        float inv = 1.f / denomS[tr * 4 + rr];
#pragma unroll
        for (int cc = 0; cc < 8; ++cc) {
            int col = c0 + tc + 32 * cc;
            size_t off = (size_t)row * D_ + col;
            out[off] = acc[rr][cc] * inv + hs[off];
        }
    }
}

// ---------------- Kernel 3a: per mem-token row: mk, denom2, nic, mb
__global__ __launch_bounds__(256) void k_mk(const float* __restrict__ out,
                                            const float* __restrict__ Wmk,
                                            const float* __restrict__ Wmb_w,
                                            const float* __restrict__ Wmb_b,
                                            const float* __restrict__ z,
                                            float* __restrict__ mk_g,
                                            float* __restrict__ scal) {
    __shared__ float memRow[D_];
    __shared__ float qpart[4][64];
    __shared__ float xv[128];
    __shared__ float mks[DK_];
    __shared__ float red[256];
    const int j = blockIdx.x;
    const int tid = threadIdx.x;
    const float* mem = out + (size_t)(S_ - NMEM_ + j) * D_;
    for (int i = tid; i < D_; i += 256) memRow[i] = mem[i];
    __syncthreads();
    {
        int c = tid & 63, seg = tid >> 6;
        float p = 0.f;
        for (int k = seg * 512; k < seg * 512 + 512; ++k)
            p += memRow[k] * Wmk[(size_t)c * D_ + k];
        qpart[seg][c] = p;
    }
    __syncthreads();
    if (tid < 64) {
        float q = qpart[0][tid] + qpart[1][tid] + qpart[2][tid] + qpart[3][tid];
        xv[tid] = fmaxf(q, 0.f);
        xv[tid + 64] = fmaxf(-q, 0.f);
    }
    __syncthreads();
    for (int m = tid; m < DK_; m += 256) {
        int i = m & 127, g = m >> 7;
        float v = xv[i] * xv[(i - g - 1) & 127];
        mks[m] = v;
        mk_g[(size_t)j * DK_ + m] = v;
    }
    __syncthreads();
    float pd = 0.f, ps = 0.f;
    for (int m = tid; m < DK_; m += 256) { float v = mks[m]; pd += v * z[m]; ps += v * v; }
    red[tid] = pd; __syncthreads();
    for (int s = 128; s > 0; s >>= 1) { if (tid < s) red[tid] += red[tid + s]; __syncthreads(); }
    float denom2 = red[0] + EPS_;
    __syncthreads();
    red[tid] = ps; __syncthreads();
    for (int s = 128; s > 0; s >>= 1) { if (tid < s) red[tid] += red[tid + s]; __syncthreads(); }
    float mksq = red[0];
    __syncthreads();
    float pb = 0.f;
    for (int k = tid; k < D_; k += 256) pb += memRow[k] * Wmb_w[k];
    red[tid] = pb; __syncthreads();
    for (int s = 128; s > 0; s >>= 1) { if (tid < s) red[tid] += red[tid + s]; __syncthreads(); }
    if (tid == 0) {
        float bsum = red[0] + Wmb_b[0];
        float mb = 1.f / (1.f + expf(-bsum));
        float nic = 1.f - denom2 / (mksq + EPS_);
        nic = fminf(fmaxf(nic, 0.f), 1.f);
        scal[j * 4 + 0] = denom2;
        scal[j * 4 + 1] = nic;
        scal[j * 4 + 2] = mb;
        scal[j * 4 + 3] = mksq;
    }
}

// ---------------- Kernel 3b: mvb = (mem@Wmv^T - (mk@W_mem)/denom2) * mb
// grid (D/64, NMEM/32), 256 threads; thread: 8 rows x 1 col
__global__ __launch_bounds__(256) void k_mv(const float* __restrict__ out,
                                            const float* __restrict__ Wmv,
                                            const float* __restrict__ Wmem,
                                            const float* __restrict__ mk_g,
                                            const float* __restrict__ scal,
                                            float* __restrict__ mvb) {
    __shared__ float bt[64][65];
    __shared__ float am[32][65];
    const int c0 = blockIdx.x * 64;
    const int rb0 = blockIdx.y * 32;
    const int tid = threadIdx.x;
    const int tc = tid & 63, tr = tid >> 6;
    float acc1[8] = {};
    for (int k0 = 0; k0 < D_; k0 += 64) {
#pragma unroll
        for (int i = 0; i < 16; ++i) {
            int flat = tid + 256 * i;
            int cc = flat >> 6, kk = flat & 63;
            bt[cc][kk] = Wmv[(size_t)(c0 + cc) * D_ + k0 + kk];
        }
#pragma unroll
        for (int i = 0; i < 8; ++i) {
            int flat = tid + 256 * i;
            int r = flat >> 6, kk = flat & 63;
            am[r][kk] = out[(size_t)(S_ - NMEM_ + rb0 + r) * D_ + k0 + kk];
        }
        __syncthreads();
#pragma unroll 16
        for (int kk = 0; kk < 64; ++kk) {
            float b_ = bt[tc][kk];
#pragma unroll
            for (int rr = 0; rr < 8; ++rr)
                acc1[rr] += am[tr * 8 + rr][kk] * b_;
        }
        __syncthreads();
    }
    float acc2[8] = {};
#pragma unroll 4
    for (int k = 0; k < DK_; ++k) {
        float b_ = Wmem[(size_t)k * D_ + c0 + tc];
#pragma unroll
        for (int rr = 0; rr < 8; ++rr)
            acc2[rr] += mk_g[(size_t)(rb0 + tr * 8 + rr) * DK_ + k] * b_;
    }
#pragma unroll
    for (int rr = 0; rr < 8; ++rr) {
        int row = rb0 + tr * 8 + rr;
        float d2 = scal[row * 4 + 0], mb = scal[row * 4 + 2];
        mvb[(size_t)row * D_ + c0 + tc] = (acc1[rr] - acc2[rr] / d2) * mb;
    }
}

// ---------------- Kernel 3c: W_mem_new = W_mem + mk^T @ mvb
// grid (D/256, DK/8), 256 threads
__global__ __launch_bounds__(256) void k_wmem(const float* __restrict__ Wmem,
                                              const float* __restrict__ mk_g,
                                              const float* __restrict__ mvb,
                                              float* __restrict__ wout) {
    const int c0 = blockIdx.x * 256;
    const int k0 = blockIdx.y * 8;
    const int tid = threadIdx.x;
    const int tk = tid >> 5, tt = tid & 31;
    float acc[8] = {};
    for (int j = 0; j < NMEM_; ++j) {
        float a = mk_g[(size_t)j * DK_ + k0 + tk];
#pragma unroll
        for (int i = 0; i < 8; ++i)
            acc[i] += a * mvb[(size_t)j * D_ + c0 + tt + 32 * i];
    }
#pragma unroll
    for (int i = 0; i < 8; ++i) {
        size_t off = (size_t)(k0 + tk) * D_ + c0 + tt + 32 * i;
        wout[off] = Wmem[off] + acc[i];
    }
}

// ---------------- Kernel 3d: z_new = z + sum_j nic[j]*mk[j,:]
__global__ void k_znew(const float* __restrict__ z,
                       const float* __restrict__ mk_g,
                       const float* __restrict__ scal,
                       float* __restrict__ zout) {
    int t = threadIdx.x;
    if (t < DK_) {
        float acc = z[t];
        for (int j = 0; j < NMEM_; ++j)
            acc += scal[j * 4 + 1] * mk_g[(size_t)j * DK_ + t];
        zout[t] = acc;
    }
}

extern "C" void kernel_launch(void* const* d_in, const int* in_sizes, int n_in,
                              void* d_out, int out_size, void* d_ws, size_t ws_size,
                              hipStream_t stream) {
    const float* hs   = (const float*)d_in[0];
    const float* Wmq  = (const float*)d_in[1];
    const float* Wmk  = (const float*)d_in[2];
    const float* Wmv  = (const float*)d_in[3];
    const float* Wmbw = (const float*)d_in[4];
    const float* Wmbb = (const float*)d_in[5];
    const float* Wmem = (const float*)d_in[6];
    const float* z    = (const float*)d_in[7];
    float* out  = (float*)d_out;
    float* wout = out + (size_t)S_ * D_;
    float* zout = wout + (size_t)DK_ * D_;
    float* ws   = (float*)d_ws;
    float* Q    = ws;                         // S*64 floats
    float* mk_g = Q + (size_t)S_ * DM_;       // 128*384
    float* scal = mk_g + (size_t)NMEM_ * DK_; // 128*4
    float* mvb  = scal + NMEM_ * 4;           // 128*2048

    k_qgemm<<<dim3(S_ / 64), 256, 0, stream>>>(hs, Wmq, Q);
    k_main<<<dim3(S_ / 32, D_ / 256), 256, 0, stream>>>(hs, Q, Wmem, z, out);
    k_mk<<<dim3(NMEM_), 256, 0, stream>>>(out, Wmk, Wmbw, Wmbb, z, mk_g, scal);
    k_mv<<<dim3(D_ / 64, NMEM_ / 32), 256, 0, stream>>>(out, Wmv, Wmem, mk_g, scal, mvb);
    k_wmem<<<dim3(D_ / 256, DK_ / 8), 256, 0, stream>>>(Wmem, mk_g, mvb, wout);
    k_znew<<<dim3(1), 384, 0, stream>>>(z, mk_g, scal, zout);
}

// Round 2
// 404.954 us; speedup vs baseline: 2.0985x; 2.0985x over previous
//
#include <hip/hip_runtime.h>
#include <hip/hip_bf16.h>
#include <math.h>

#define S_ 16384
#define D_ 2048
#define DM_ 64
#define DK_ 384
#define NMEM_ 128
#define EPS_ 1e-5f

typedef __attribute__((ext_vector_type(8))) short bf16x8;
typedef __attribute__((ext_vector_type(4))) float f32x4;
typedef unsigned short u16;

static __device__ __forceinline__ u16 f2bf(float x) {
    __hip_bfloat16 h = __float2bfloat16(x);
    return *reinterpret_cast<u16*>(&h);
}

static __device__ __forceinline__ void gload16(const void* g, void* l) {
    __builtin_amdgcn_global_load_lds(
        (const __attribute__((address_space(1))) unsigned int*)g,
        (__attribute__((address_space(3))) unsigned int*)l, 16, 0, 0);
}

// ---------------- conv: Wmq f32[64][2048] -> bf16 (already B^T layout)
__global__ void k_convWmq(const float* __restrict__ Wmq, u16* __restrict__ Wmq_b) {
    int idx = (blockIdx.x * 256 + threadIdx.x) * 4;
    float4 v = *reinterpret_cast<const float4*>(&Wmq[idx]);
    ushort4 p;
    p.x = f2bf(v.x); p.y = f2bf(v.y); p.z = f2bf(v.z); p.w = f2bf(v.w);
    *reinterpret_cast<ushort4*>(&Wmq_b[idx]) = p;
}

// ---------------- conv: W_mem f32[384][2048] -> WmT bf16[2048][384]
__global__ __launch_bounds__(256) void k_convWT(const float* __restrict__ Wmem,
                                                u16* __restrict__ WmT) {
    __shared__ float ts[32][33];
    const int c0 = blockIdx.x * 32, k0 = blockIdx.y * 32;
    const int tx = threadIdx.x & 31, ty = threadIdx.x >> 5;
#pragma unroll
    for (int i = 0; i < 4; ++i)
        ts[ty + 8 * i][tx] = Wmem[(size_t)(k0 + ty + 8 * i) * D_ + c0 + tx];
    __syncthreads();
#pragma unroll
    for (int i = 0; i < 4; ++i)
        WmT[(size_t)(c0 + ty + 8 * i) * DK_ + k0 + tx] = f2bf(ts[tx][ty + 8 * i]);
}

// ---------------- Kernel 1: Q = hs @ Wmq^T via MFMA, A reg-staged f32->bf16
// BM=128, BN=64, BK=64; 256 thr = 4 waves, wave w: rows w*32..+31, all 64 cols
__global__ __launch_bounds__(256) void k_qgemm(const float* __restrict__ hs,
                                               const u16* __restrict__ Wmq_b,
                                               float* __restrict__ Q) {
    __shared__ u16 As[128 * 64];
    __shared__ u16 Bs[64 * 64];
    const int r0 = blockIdx.x * 128;
    const int tid = threadIdx.x;
    const int lane = tid & 63, w = tid >> 6;
    const int lrow = lane & 15, lkg = lane >> 4;
    f32x4 acc[2][4];
    const f32x4 zero4 = {0.f, 0.f, 0.f, 0.f};
#pragma unroll
    for (int m = 0; m < 2; ++m)
#pragma unroll
        for (int n = 0; n < 4; ++n) acc[m][n] = zero4;
    for (int kc = 0; kc < D_ / 64; ++kc) {
        // A: load f32, cvt, swizzled ds_write (slot g holds global granule g^(row&7))
#pragma unroll
        for (int i = 0; i < 8; ++i) {
            int flat4 = tid + 256 * i;
            int row = flat4 >> 4, c4 = flat4 & 15;
            const float4 v = *reinterpret_cast<const float4*>(
                &hs[(size_t)(r0 + row) * D_ + kc * 64 + c4 * 4]);
            int off = row * 64 + (((c4 >> 1) ^ (row & 7)) * 8) + (c4 & 1) * 4;
            ushort4 p;
            p.x = f2bf(v.x); p.y = f2bf(v.y); p.z = f2bf(v.z); p.w = f2bf(v.w);
            *reinterpret_cast<ushort4*>(&As[off]) = p;
        }
        // B: global_load_lds, pre-swizzled source, linear dest
#pragma unroll
        for (int i = 0; i < 2; ++i) {
            int col = w * 16 + i * 8 + (lane >> 3);
            int gg = (lane & 7) ^ (col & 7);
            gload16(Wmq_b + (size_t)col * D_ + kc * 64 + gg * 8,
                    &Bs[(w * 16 + i * 8) * 64]);
        }
        __syncthreads();
#pragma unroll
        for (int s = 0; s < 2; ++s) {
            bf16x8 af[2], bb[4];
#pragma unroll
            for (int m = 0; m < 2; ++m) {
                int rl = w * 32 + m * 16 + lrow;
                af[m] = *reinterpret_cast<const bf16x8*>(
                    &As[rl * 64 + (((s * 4 + lkg) ^ (rl & 7)) * 8)]);
            }
#pragma unroll
            for (int n = 0; n < 4; ++n) {
                int cl = n * 16 + lrow;
                bb[n] = *reinterpret_cast<const bf16x8*>(
                    &Bs[cl * 64 + (((s * 4 + lkg) ^ (cl & 7)) * 8)]);
            }
#pragma unroll
            for (int m = 0; m < 2; ++m)
#pragma unroll
                for (int n = 0; n < 4; ++n)
                    acc[m][n] = __builtin_amdgcn_mfma_f32_16x16x32_bf16(
                        af[m], bb[n], acc[m][n], 0, 0, 0);
        }
        __syncthreads();
    }
#pragma unroll
    for (int m = 0; m < 2; ++m)
#pragma unroll
        for (int n = 0; n < 4; ++n)
#pragma unroll
            for (int r = 0; r < 4; ++r) {
                int row = r0 + w * 32 + m * 16 + lkg * 4 + r;
                Q[(size_t)row * DM_ + n * 16 + lrow] = acc[m][n][r];
            }
}

// ---------------- Kernel 2: dpfp(Q) -> mq bf16 [S][384], denom -> denomv [S]
// 1 wave per row, 4 rows per block
__global__ __launch_bounds__(256) void k_dpfp(const float* __restrict__ Q,
                                              const float* __restrict__ z,
                                              u16* __restrict__ mq_b,
                                              float* __restrict__ denomv) {
    __shared__ float xw[4][128];
    const int tid = threadIdx.x;
    const int lane = tid & 63, w = tid >> 6;
    const int row = blockIdx.x * 4 + w;
    float q = Q[(size_t)row * DM_ + lane];
    xw[w][lane] = fmaxf(q, 0.f);
    xw[w][lane + 64] = fmaxf(-q, 0.f);
    __syncthreads();
    float pd = 0.f;
#pragma unroll
    for (int gi = 0; gi < 6; ++gi) {
        int m = gi * 64 + lane;
        int grp = m >> 7, i = m & 127;
        float v = xw[w][i] * xw[w][(i - grp - 1) & 127];
        mq_b[(size_t)row * DK_ + m] = f2bf(v);
        pd += z[m] * v;
    }
#pragma unroll
    for (int off = 32; off > 0; off >>= 1) pd += __shfl_down(pd, off);
    if (lane == 0) denomv[row] = pd + EPS_;
}

// ---------------- Kernel 3: out = (mq @ WmT^T)/denom + hs via MFMA
// BM=BN=128, BK=64, 4 waves 2x2, each wave 64x64 (4x4 frags)
__global__ __launch_bounds__(256) void k_main(const float* __restrict__ hs,
                                              const u16* __restrict__ mq_b,
                                              const u16* __restrict__ WmT,
                                              const float* __restrict__ denomv,
                                              float* __restrict__ out) {
    __shared__ u16 At[128 * 64];
    __shared__ u16 Bt[128 * 64];
    __shared__ float dinv[128];
    const int bid = blockIdx.x;
    const int swz = (bid & 7) * 256 + (bid >> 3);   // XCD chunked, 2048 % 8 == 0
    const int r0 = (swz >> 4) * 128, c0 = (swz & 15) * 128;
    const int tid = threadIdx.x;
    const int lane = tid & 63, w = tid >> 6;
    const int lrow = lane & 15, lkg = lane >> 4;
    const int wr = w >> 1, wc = w & 1;
    if (tid < 128) dinv[tid] = 1.f / denomv[r0 + tid];
    f32x4 acc[4][4];
    const f32x4 zero4 = {0.f, 0.f, 0.f, 0.f};
#pragma unroll
    for (int m = 0; m < 4; ++m)
#pragma unroll
        for (int n = 0; n < 4; ++n) acc[m][n] = zero4;
    for (int kc = 0; kc < 6; ++kc) {
        // wave w stages rows/cols w*32..+31; 8 global_load_lds per wave
#pragma unroll
        for (int i = 0; i < 4; ++i) {
            int rr = w * 32 + i * 8 + (lane >> 3);
            int gg = (lane & 7) ^ (rr & 7);
            gload16(mq_b + (size_t)(r0 + rr) * DK_ + kc * 64 + gg * 8,
                    &At[(w * 32 + i * 8) * 64]);
            gload16(WmT + (size_t)(c0 + rr) * DK_ + kc * 64 + gg * 8,
                    &Bt[(w * 32 + i * 8) * 64]);
        }
        __syncthreads();
#pragma unroll
        for (int s = 0; s < 2; ++s) {
            bf16x8 af[4], bb[4];
#pragma unroll
            for (int m = 0; m < 4; ++m) {
                int rl = wr * 64 + m * 16 + lrow;
                af[m] = *reinterpret_cast<const bf16x8*>(
                    &At[rl * 64 + (((s * 4 + lkg) ^ (rl & 7)) * 8)]);
            }
#pragma unroll
            for (int n = 0; n < 4; ++n) {
                int cl = wc * 64 + n * 16 + lrow;
                bb[n] = *reinterpret_cast<const bf16x8*>(
                    &Bt[cl * 64 + (((s * 4 + lkg) ^ (cl & 7)) * 8)]);
            }
#pragma unroll
            for (int m = 0; m < 4; ++m)
#pragma unroll
                for (int n = 0; n < 4; ++n)
                    acc[m][n] = __builtin_amdgcn_mfma_f32_16x16x32_bf16(
                        af[m], bb[n], acc[m][n], 0, 0, 0);
        }
        __syncthreads();
    }
#pragma unroll
    for (int m = 0; m < 4; ++m)
#pragma unroll
        for (int n = 0; n < 4; ++n) {
            int colg = c0 + wc * 64 + n * 16 + lrow;
#pragma unroll
            for (int r = 0; r < 4; ++r) {
                int rowl = wr * 64 + m * 16 + lkg * 4 + r;
                size_t off = (size_t)(r0 + rowl) * D_ + colg;
                out[off] = acc[m][n][r] * dinv[rowl] + hs[off];
            }
        }
}

// ---------------- Kernel 4a: per mem-token row: mk, denom2, nic, mb (f32)
__global__ __launch_bounds__(256) void k_mk(const float* __restrict__ out,
                                            const float* __restrict__ Wmk,
                                            const float* __restrict__ Wmb_w,
                                            const float* __restrict__ Wmb_b,
                                            const float* __restrict__ z,
                                            float* __restrict__ mk_g,
                                            float* __restrict__ scal) {
    __shared__ float memRow[D_];
    __shared__ float qpart[4][64];
    __shared__ float xv[128];
    __shared__ float mks[DK_];
    __shared__ float red[256];
    const int j = blockIdx.x;
    const int tid = threadIdx.x;
    const float* mem = out + (size_t)(S_ - NMEM_ + j) * D_;
    for (int i = tid; i < D_; i += 256) memRow[i] = mem[i];
    __syncthreads();
    {
        int c = tid & 63, seg = tid >> 6;
        float p = 0.f;
        for (int k = seg * 512; k < seg * 512 + 512; ++k)
            p += memRow[k] * Wmk[(size_t)c * D_ + k];
        qpart[seg][c] = p;
    }
    __syncthreads();
    if (tid < 64) {
        float q = qpart[0][tid] + qpart[1][tid] + qpart[2][tid] + qpart[3][tid];
        xv[tid] = fmaxf(q, 0.f);
        xv[tid + 64] = fmaxf(-q, 0.f);
    }
    __syncthreads();
    for (int m = tid; m < DK_; m += 256) {
        int i = m & 127, g = m >> 7;
        float v = xv[i] * xv[(i - g - 1) & 127];
        mks[m] = v;
        mk_g[(size_t)j * DK_ + m] = v;
    }
    __syncthreads();
    float pd = 0.f, ps = 0.f;
    for (int m = tid; m < DK_; m += 256) { float v = mks[m]; pd += v * z[m]; ps += v * v; }
    red[tid] = pd; __syncthreads();
    for (int s = 128; s > 0; s >>= 1) { if (tid < s) red[tid] += red[tid + s]; __syncthreads(); }
    float denom2 = red[0] + EPS_;
    __syncthreads();
    red[tid] = ps; __syncthreads();
    for (int s = 128; s > 0; s >>= 1) { if (tid < s) red[tid] += red[tid + s]; __syncthreads(); }
    float mksq = red[0];
    __syncthreads();
    float pb = 0.f;
    for (int k = tid; k < D_; k += 256) pb += memRow[k] * Wmb_w[k];
    red[tid] = pb; __syncthreads();
    for (int s = 128; s > 0; s >>= 1) { if (tid < s) red[tid] += red[tid + s]; __syncthreads(); }
    if (tid == 0) {
        float bsum = red[0] + Wmb_b[0];
        float mb = 1.f / (1.f + expf(-bsum));
        float nic = 1.f - denom2 / (mksq + EPS_);
        nic = fminf(fmaxf(nic, 0.f), 1.f);
        scal[j * 4 + 0] = denom2;
        scal[j * 4 + 1] = nic;
        scal[j * 4 + 2] = mb;
        scal[j * 4 + 3] = mksq;
    }
}

// ---------------- Kernel 4b: mvb = (mem@Wmv^T - (mk@W_mem)/denom2) * mb
__global__ __launch_bounds__(256) void k_mv(const float* __restrict__ out,
                                            const float* __restrict__ Wmv,
                                            const float* __restrict__ Wmem,
                                            const float* __restrict__ mk_g,
                                            const float* __restrict__ scal,
                                            float* __restrict__ mvb) {
    __shared__ float bt[64][65];
    __shared__ float am[32][65];
    const int c0 = blockIdx.x * 64;
    const int rb0 = blockIdx.y * 32;
    const int tid = threadIdx.x;
    const int tc = tid & 63, tr = tid >> 6;
    float acc1[8] = {};
    for (int k0 = 0; k0 < D_; k0 += 64) {
#pragma unroll
        for (int i = 0; i < 16; ++i) {
            int flat = tid + 256 * i;
            int cc = flat >> 6, kk = flat & 63;
            bt[cc][kk] = Wmv[(size_t)(c0 + cc) * D_ + k0 + kk];
        }
#pragma unroll
        for (int i = 0; i < 8; ++i) {
            int flat = tid + 256 * i;
            int r = flat >> 6, kk = flat & 63;
            am[r][kk] = out[(size_t)(S_ - NMEM_ + rb0 + r) * D_ + k0 + kk];
        }
        __syncthreads();
#pragma unroll 16
        for (int kk = 0; kk < 64; ++kk) {
            float b_ = bt[tc][kk];
#pragma unroll
            for (int rr = 0; rr < 8; ++rr)
                acc1[rr] += am[tr * 8 + rr][kk] * b_;
        }
        __syncthreads();
    }
    float acc2[8] = {};
#pragma unroll 4
    for (int k = 0; k < DK_; ++k) {
        float b_ = Wmem[(size_t)k * D_ + c0 + tc];
#pragma unroll
        for (int rr = 0; rr < 8; ++rr)
            acc2[rr] += mk_g[(size_t)(rb0 + tr * 8 + rr) * DK_ + k] * b_;
    }
#pragma unroll
    for (int rr = 0; rr < 8; ++rr) {
        int row = rb0 + tr * 8 + rr;
        float d2 = scal[row * 4 + 0], mb = scal[row * 4 + 2];
        mvb[(size_t)row * D_ + c0 + tc] = (acc1[rr] - acc2[rr] / d2) * mb;
    }
}

// ---------------- Kernel 4c: W_mem_new = W_mem + mk^T @ mvb
__global__ __launch_bounds__(256) void k_wmem(const float* __restrict__ Wmem,
                                              const float* __restrict__ mk_g,
                                              const float* __restrict__ mvb,
                                              float* __restrict__ wout) {
    const int c0 = blockIdx.x * 256;
    const int k0 = blockIdx.y * 8;
    const int tid = threadIdx.x;
    const int tk = tid >> 5, tt = tid & 31;
    float acc[8] = {};
    for (int j = 0; j < NMEM_; ++j) {
        float a = mk_g[(size_t)j * DK_ + k0 + tk];
#pragma unroll
        for (int i = 0; i < 8; ++i)
            acc[i] += a * mvb[(size_t)j * D_ + c0 + tt + 32 * i];
    }
#pragma unroll
    for (int i = 0; i < 8; ++i) {
        size_t off = (size_t)(k0 + tk) * D_ + c0 + tt + 32 * i;
        wout[off] = Wmem[off] + acc[i];
    }
}

// ---------------- Kernel 4d: z_new = z + sum_j nic[j]*mk[j,:]
__global__ void k_znew(const float* __restrict__ z,
                       const float* __restrict__ mk_g,
                       const float* __restrict__ scal,
                       float* __restrict__ zout) {
    int t = threadIdx.x;
    if (t < DK_) {
        float acc = z[t];
        for (int j = 0; j < NMEM_; ++j)
            acc += scal[j * 4 + 1] * mk_g[(size_t)j * DK_ + t];
        zout[t] = acc;
    }
}

extern "C" void kernel_launch(void* const* d_in, const int* in_sizes, int n_in,
                              void* d_out, int out_size, void* d_ws, size_t ws_size,
                              hipStream_t stream) {
    const float* hs   = (const float*)d_in[0];
    const float* Wmq  = (const float*)d_in[1];
    const float* Wmk  = (const float*)d_in[2];
    const float* Wmv  = (const float*)d_in[3];
    const float* Wmbw = (const float*)d_in[4];
    const float* Wmbb = (const float*)d_in[5];
    const float* Wmem = (const float*)d_in[6];
    const float* z    = (const float*)d_in[7];
    float* out  = (float*)d_out;
    float* wout = out + (size_t)S_ * D_;
    float* zout = wout + (size_t)DK_ * D_;

    float* ws = (float*)d_ws;
    float* Q      = ws;                              // 16384*64
    float* denomv = Q + (size_t)S_ * DM_;            // 16384
    float* mk_g   = denomv + S_;                     // 128*384
    float* scal   = mk_g + (size_t)NMEM_ * DK_;      // 512
    float* mvb    = scal + NMEM_ * 4;                // 128*2048
    u16* mq_b  = (u16*)(mvb + (size_t)NMEM_ * D_);   // 16384*384 bf16
    u16* WmT   = mq_b + (size_t)S_ * DK_;            // 2048*384 bf16
    u16* Wmq_b = WmT + (size_t)D_ * DK_;             // 64*2048 bf16

    k_convWmq<<<dim3(128), 256, 0, stream>>>(Wmq, Wmq_b);
    k_convWT<<<dim3(D_ / 32, DK_ / 32), 256, 0, stream>>>(Wmem, WmT);
    k_qgemm<<<dim3(S_ / 128), 256, 0, stream>>>(hs, Wmq_b, Q);
    k_dpfp<<<dim3(S_ / 4), 256, 0, stream>>>(Q, z, mq_b, denomv);
    k_main<<<dim3((S_ / 128) * (D_ / 128)), 256, 0, stream>>>(hs, mq_b, WmT, denomv, out);
    k_mk<<<dim3(NMEM_), 256, 0, stream>>>(out, Wmk, Wmbw, Wmbb, z, mk_g, scal);
    k_mv<<<dim3(D_ / 64, NMEM_ / 32), 256, 0, stream>>>(out, Wmv, Wmem, mk_g, scal, mvb);
    k_wmem<<<dim3(D_ / 256, DK_ / 8), 256, 0, stream>>>(Wmem, mk_g, mvb, wout);
    k_znew<<<dim3(1), 384, 0, stream>>>(z, mk_g, scal, zout);
}

// Round 3
// 245.760 us; speedup vs baseline: 3.4578x; 1.6478x over previous
//
#include <hip/hip_runtime.h>
#include <hip/hip_bf16.h>
#include <math.h>

#define S_ 16384
#define D_ 2048
#define DM_ 64
#define DK_ 384
#define NMEM_ 128
#define EPS_ 1e-5f

typedef __attribute__((ext_vector_type(8))) short bf16x8;
typedef __attribute__((ext_vector_type(4))) float f32x4;
typedef unsigned short u16;

static __device__ __forceinline__ u16 f2bf(float x) {
    __hip_bfloat16 h = __float2bfloat16(x);
    return *reinterpret_cast<u16*>(&h);
}

static __device__ __forceinline__ void gload16(const void* g, void* l) {
    __builtin_amdgcn_global_load_lds(
        (const __attribute__((address_space(1))) unsigned int*)g,
        (__attribute__((address_space(3))) unsigned int*)l, 16, 0, 0);
}

// ---------------- conv: Wmq f32[64][2048] -> bf16 (already B^T layout)
__global__ void k_convWmq(const float* __restrict__ Wmq, u16* __restrict__ Wmq_b) {
    int idx = (blockIdx.x * 256 + threadIdx.x) * 4;
    float4 v = *reinterpret_cast<const float4*>(&Wmq[idx]);
    ushort4 p;
    p.x = f2bf(v.x); p.y = f2bf(v.y); p.z = f2bf(v.z); p.w = f2bf(v.w);
    *reinterpret_cast<ushort4*>(&Wmq_b[idx]) = p;
}

// ---------------- conv: Wmv f32[2048][2048] -> bf16 (already B^T layout)
__global__ void k_convWmv(const float* __restrict__ Wmv, u16* __restrict__ Wmv_b) {
    size_t idx = ((size_t)blockIdx.x * 256 + threadIdx.x) * 4;
    float4 v = *reinterpret_cast<const float4*>(&Wmv[idx]);
    ushort4 p;
    p.x = f2bf(v.x); p.y = f2bf(v.y); p.z = f2bf(v.z); p.w = f2bf(v.w);
    *reinterpret_cast<ushort4*>(&Wmv_b[idx]) = p;
}

// ---------------- conv: W_mem f32[384][2048] -> WmT bf16[2048][384]
__global__ __launch_bounds__(256) void k_convWT(const float* __restrict__ Wmem,
                                                u16* __restrict__ WmT) {
    __shared__ float ts[32][33];
    const int c0 = blockIdx.x * 32, k0 = blockIdx.y * 32;
    const int tx = threadIdx.x & 31, ty = threadIdx.x >> 5;
#pragma unroll
    for (int i = 0; i < 4; ++i)
        ts[ty + 8 * i][tx] = Wmem[(size_t)(k0 + ty + 8 * i) * D_ + c0 + tx];
    __syncthreads();
#pragma unroll
    for (int i = 0; i < 4; ++i)
        WmT[(size_t)(c0 + ty + 8 * i) * DK_ + k0 + tx] = f2bf(ts[tx][ty + 8 * i]);
}

// ---------------- extract last-128 rows of out as bf16 [128][2048]
__global__ void k_memb(const float* __restrict__ out, u16* __restrict__ mem_b) {
    int idx = (blockIdx.x * 256 + threadIdx.x) * 4;
    const float* src = out + (size_t)(S_ - NMEM_) * D_;
    float4 v = *reinterpret_cast<const float4*>(&src[idx]);
    ushort4 p;
    p.x = f2bf(v.x); p.y = f2bf(v.y); p.z = f2bf(v.z); p.w = f2bf(v.w);
    *reinterpret_cast<ushort4*>(&mem_b[idx]) = p;
}

// ---------------- Kernel 1: Q = hs @ Wmq^T via MFMA, A reg-staged f32->bf16
__global__ __launch_bounds__(256) void k_qgemm(const float* __restrict__ hs,
                                               const u16* __restrict__ Wmq_b,
                                               float* __restrict__ Q) {
    __shared__ u16 As[128 * 64];
    __shared__ u16 Bs[64 * 64];
    const int r0 = blockIdx.x * 128;
    const int tid = threadIdx.x;
    const int lane = tid & 63, w = tid >> 6;
    const int lrow = lane & 15, lkg = lane >> 4;
    f32x4 acc[2][4];
    const f32x4 zero4 = {0.f, 0.f, 0.f, 0.f};
#pragma unroll
    for (int m = 0; m < 2; ++m)
#pragma unroll
        for (int n = 0; n < 4; ++n) acc[m][n] = zero4;
    for (int kc = 0; kc < D_ / 64; ++kc) {
#pragma unroll
        for (int i = 0; i < 8; ++i) {
            int flat4 = tid + 256 * i;
            int row = flat4 >> 4, c4 = flat4 & 15;
            const float4 v = *reinterpret_cast<const float4*>(
                &hs[(size_t)(r0 + row) * D_ + kc * 64 + c4 * 4]);
            int off = row * 64 + (((c4 >> 1) ^ (row & 7)) * 8) + (c4 & 1) * 4;
            ushort4 p;
            p.x = f2bf(v.x); p.y = f2bf(v.y); p.z = f2bf(v.z); p.w = f2bf(v.w);
            *reinterpret_cast<ushort4*>(&As[off]) = p;
        }
#pragma unroll
        for (int i = 0; i < 2; ++i) {
            int col = w * 16 + i * 8 + (lane >> 3);
            int gg = (lane & 7) ^ (col & 7);
            gload16(Wmq_b + (size_t)col * D_ + kc * 64 + gg * 8,
                    &Bs[(w * 16 + i * 8) * 64]);
        }
        __syncthreads();
#pragma unroll
        for (int s = 0; s < 2; ++s) {
            bf16x8 af[2], bb[4];
#pragma unroll
            for (int m = 0; m < 2; ++m) {
                int rl = w * 32 + m * 16 + lrow;
                af[m] = *reinterpret_cast<const bf16x8*>(
                    &As[rl * 64 + (((s * 4 + lkg) ^ (rl & 7)) * 8)]);
            }
#pragma unroll
            for (int n = 0; n < 4; ++n) {
                int cl = n * 16 + lrow;
                bb[n] = *reinterpret_cast<const bf16x8*>(
                    &Bs[cl * 64 + (((s * 4 + lkg) ^ (cl & 7)) * 8)]);
            }
#pragma unroll
            for (int m = 0; m < 2; ++m)
#pragma unroll
                for (int n = 0; n < 4; ++n)
                    acc[m][n] = __builtin_amdgcn_mfma_f32_16x16x32_bf16(
                        af[m], bb[n], acc[m][n], 0, 0, 0);
        }
        __syncthreads();
    }
#pragma unroll
    for (int m = 0; m < 2; ++m)
#pragma unroll
        for (int n = 0; n < 4; ++n)
#pragma unroll
            for (int r = 0; r < 4; ++r) {
                int row = r0 + w * 32 + m * 16 + lkg * 4 + r;
                Q[(size_t)row * DM_ + n * 16 + lrow] = acc[m][n][r];
            }
}

// ---------------- Kernel 2: dpfp(Q) -> mq bf16 [S][384], denom -> denomv [S]
__global__ __launch_bounds__(256) void k_dpfp(const float* __restrict__ Q,
                                              const float* __restrict__ z,
                                              u16* __restrict__ mq_b,
                                              float* __restrict__ denomv) {
    __shared__ float xw[4][128];
    const int tid = threadIdx.x;
    const int lane = tid & 63, w = tid >> 6;
    const int row = blockIdx.x * 4 + w;
    float q = Q[(size_t)row * DM_ + lane];
    xw[w][lane] = fmaxf(q, 0.f);
    xw[w][lane + 64] = fmaxf(-q, 0.f);
    __syncthreads();
    float pd = 0.f;
#pragma unroll
    for (int gi = 0; gi < 6; ++gi) {
        int m = gi * 64 + lane;
        int grp = m >> 7, i = m & 127;
        float v = xw[w][i] * xw[w][(i - grp - 1) & 127];
        mq_b[(size_t)row * DK_ + m] = f2bf(v);
        pd += z[m] * v;
    }
#pragma unroll
    for (int off = 32; off > 0; off >>= 1) pd += __shfl_down(pd, off);
    if (lane == 0) denomv[row] = pd + EPS_;
}

// ---------------- Kernel 3: out = (mq @ WmT^T)/denom + hs via MFMA
__global__ __launch_bounds__(256) void k_main(const float* __restrict__ hs,
                                              const u16* __restrict__ mq_b,
                                              const u16* __restrict__ WmT,
                                              const float* __restrict__ denomv,
                                              float* __restrict__ out) {
    __shared__ u16 At[128 * 64];
    __shared__ u16 Bt[128 * 64];
    __shared__ float dinv[128];
    const int bid = blockIdx.x;
    const int swz = (bid & 7) * 256 + (bid >> 3);   // XCD chunked, 2048 % 8 == 0
    const int r0 = (swz >> 4) * 128, c0 = (swz & 15) * 128;
    const int tid = threadIdx.x;
    const int lane = tid & 63, w = tid >> 6;
    const int lrow = lane & 15, lkg = lane >> 4;
    const int wr = w >> 1, wc = w & 1;
    if (tid < 128) dinv[tid] = 1.f / denomv[r0 + tid];
    f32x4 acc[4][4];
    const f32x4 zero4 = {0.f, 0.f, 0.f, 0.f};
#pragma unroll
    for (int m = 0; m < 4; ++m)
#pragma unroll
        for (int n = 0; n < 4; ++n) acc[m][n] = zero4;
    for (int kc = 0; kc < 6; ++kc) {
#pragma unroll
        for (int i = 0; i < 4; ++i) {
            int rr = w * 32 + i * 8 + (lane >> 3);
            int gg = (lane & 7) ^ (rr & 7);
            gload16(mq_b + (size_t)(r0 + rr) * DK_ + kc * 64 + gg * 8,
                    &At[(w * 32 + i * 8) * 64]);
            gload16(WmT + (size_t)(c0 + rr) * DK_ + kc * 64 + gg * 8,
                    &Bt[(w * 32 + i * 8) * 64]);
        }
        __syncthreads();
#pragma unroll
        for (int s = 0; s < 2; ++s) {
            bf16x8 af[4], bb[4];
#pragma unroll
            for (int m = 0; m < 4; ++m) {
                int rl = wr * 64 + m * 16 + lrow;
                af[m] = *reinterpret_cast<const bf16x8*>(
                    &At[rl * 64 + (((s * 4 + lkg) ^ (rl & 7)) * 8)]);
            }
#pragma unroll
            for (int n = 0; n < 4; ++n) {
                int cl = wc * 64 + n * 16 + lrow;
                bb[n] = *reinterpret_cast<const bf16x8*>(
                    &Bt[cl * 64 + (((s * 4 + lkg) ^ (cl & 7)) * 8)]);
            }
#pragma unroll
            for (int m = 0; m < 4; ++m)
#pragma unroll
                for (int n = 0; n < 4; ++n)
                    acc[m][n] = __builtin_amdgcn_mfma_f32_16x16x32_bf16(
                        af[m], bb[n], acc[m][n], 0, 0, 0);
        }
        __syncthreads();
    }
#pragma unroll
    for (int m = 0; m < 4; ++m)
#pragma unroll
        for (int n = 0; n < 4; ++n) {
            int colg = c0 + wc * 64 + n * 16 + lrow;
#pragma unroll
            for (int r = 0; r < 4; ++r) {
                int rowl = wr * 64 + m * 16 + lkg * 4 + r;
                size_t off = (size_t)(r0 + rowl) * D_ + colg;
                out[off] = acc[m][n][r] * dinv[rowl] + hs[off];
            }
        }
}

// ---------------- Kernel 4a: per mem-token row: mk, denom2, nic, mb (f32)
__global__ __launch_bounds__(256) void k_mk(const float* __restrict__ out,
                                            const float* __restrict__ Wmk,
                                            const float* __restrict__ Wmb_w,
                                            const float* __restrict__ Wmb_b,
                                            const float* __restrict__ z,
                                            float* __restrict__ mk_g,
                                            u16* __restrict__ mk_b,
                                            float* __restrict__ scal) {
    __shared__ float memRow[D_];
    __shared__ float qpart[4][64];
    __shared__ float xv[128];
    __shared__ float mks[DK_];
    __shared__ float red[256];
    const int j = blockIdx.x;
    const int tid = threadIdx.x;
    const float* mem = out + (size_t)(S_ - NMEM_ + j) * D_;
    for (int i = tid; i < D_; i += 256) memRow[i] = mem[i];
    __syncthreads();
    {
        int c = tid & 63, seg = tid >> 6;
        float p = 0.f;
        for (int k = seg * 512; k < seg * 512 + 512; ++k)
            p += memRow[k] * Wmk[(size_t)c * D_ + k];
        qpart[seg][c] = p;
    }
    __syncthreads();
    if (tid < 64) {
        float q = qpart[0][tid] + qpart[1][tid] + qpart[2][tid] + qpart[3][tid];
        xv[tid] = fmaxf(q, 0.f);
        xv[tid + 64] = fmaxf(-q, 0.f);
    }
    __syncthreads();
    for (int m = tid; m < DK_; m += 256) {
        int i = m & 127, g = m >> 7;
        float v = xv[i] * xv[(i - g - 1) & 127];
        mks[m] = v;
        mk_g[(size_t)j * DK_ + m] = v;
        mk_b[(size_t)j * DK_ + m] = f2bf(v);
    }
    __syncthreads();
    float pd = 0.f, ps = 0.f;
    for (int m = tid; m < DK_; m += 256) { float v = mks[m]; pd += v * z[m]; ps += v * v; }
    red[tid] = pd; __syncthreads();
    for (int s = 128; s > 0; s >>= 1) { if (tid < s) red[tid] += red[tid + s]; __syncthreads(); }
    float denom2 = red[0] + EPS_;
    __syncthreads();
    red[tid] = ps; __syncthreads();
    for (int s = 128; s > 0; s >>= 1) { if (tid < s) red[tid] += red[tid + s]; __syncthreads(); }
    float mksq = red[0];
    __syncthreads();
    float pb = 0.f;
    for (int k = tid; k < D_; k += 256) pb += memRow[k] * Wmb_w[k];
    red[tid] = pb; __syncthreads();
    for (int s = 128; s > 0; s >>= 1) { if (tid < s) red[tid] += red[tid + s]; __syncthreads(); }
    if (tid == 0) {
        float bsum = red[0] + Wmb_b[0];
        float mb = 1.f / (1.f + expf(-bsum));
        float nic = 1.f - denom2 / (mksq + EPS_);
        nic = fminf(fmaxf(nic, 0.f), 1.f);
        scal[j * 4 + 0] = denom2;
        scal[j * 4 + 1] = nic;
        scal[j * 4 + 2] = mb;
        scal[j * 4 + 3] = mksq;
    }
}

// ---------------- Kernel 4b (MFMA): mvb = (mem@Wmv^T - (mk@W_mem)/denom2)*mb
// BM=128 (all mem rows), BN=128, BK=64; grid = D_/128 = 16 blocks
__global__ __launch_bounds__(256) void k_mv(const u16* __restrict__ mem_b,
                                            const u16* __restrict__ Wmv_b,
                                            const u16* __restrict__ mk_b,
                                            const u16* __restrict__ WmT,
                                            const float* __restrict__ scal,
                                            float* __restrict__ mvb) {
    __shared__ u16 At[128 * 64];
    __shared__ u16 Bt[128 * 64];
    __shared__ float inv2[128];
    __shared__ float mbl[128];
    const int c0 = blockIdx.x * 128;
    const int tid = threadIdx.x;
    const int lane = tid & 63, w = tid >> 6;
    const int lrow = lane & 15, lkg = lane >> 4;
    const int wr = w >> 1, wc = w & 1;
    if (tid < 128) {
        inv2[tid] = 1.f / scal[tid * 4 + 0];
        mbl[tid] = scal[tid * 4 + 2];
    }
    f32x4 acc1[4][4], acc2[4][4];
    const f32x4 zero4 = {0.f, 0.f, 0.f, 0.f};
#pragma unroll
    for (int m = 0; m < 4; ++m)
#pragma unroll
        for (int n = 0; n < 4; ++n) { acc1[m][n] = zero4; acc2[m][n] = zero4; }
    // ---- loop 1: mem_b @ Wmv_b^T, K = 2048
    for (int kc = 0; kc < D_ / 64; ++kc) {
#pragma unroll
        for (int i = 0; i < 4; ++i) {
            int rr = w * 32 + i * 8 + (lane >> 3);
            int gg = (lane & 7) ^ (rr & 7);
            gload16(mem_b + (size_t)rr * D_ + kc * 64 + gg * 8,
                    &At[(w * 32 + i * 8) * 64]);
            gload16(Wmv_b + (size_t)(c0 + rr) * D_ + kc * 64 + gg * 8,
                    &Bt[(w * 32 + i * 8) * 64]);
        }
        __syncthreads();
#pragma unroll
        for (int s = 0; s < 2; ++s) {
            bf16x8 af[4], bb[4];
#pragma unroll
            for (int m = 0; m < 4; ++m) {
                int rl = wr * 64 + m * 16 + lrow;
                af[m] = *reinterpret_cast<const bf16x8*>(
                    &At[rl * 64 + (((s * 4 + lkg) ^ (rl & 7)) * 8)]);
            }
#pragma unroll
            for (int n = 0; n < 4; ++n) {
                int cl = wc * 64 + n * 16 + lrow;
                bb[n] = *reinterpret_cast<const bf16x8*>(
                    &Bt[cl * 64 + (((s * 4 + lkg) ^ (cl & 7)) * 8)]);
            }
#pragma unroll
            for (int m = 0; m < 4; ++m)
#pragma unroll
                for (int n = 0; n < 4; ++n)
                    acc1[m][n] = __builtin_amdgcn_mfma_f32_16x16x32_bf16(
                        af[m], bb[n], acc1[m][n], 0, 0, 0);
        }
        __syncthreads();
    }
    // ---- loop 2: mk_b @ WmT^T, K = 384
    for (int kc = 0; kc < 6; ++kc) {
#pragma unroll
        for (int i = 0; i < 4; ++i) {
            int rr = w * 32 + i * 8 + (lane >> 3);
            int gg = (lane & 7) ^ (rr & 7);
            gload16(mk_b + (size_t)rr * DK_ + kc * 64 + gg * 8,
                    &At[(w * 32 + i * 8) * 64]);
            gload16(WmT + (size_t)(c0 + rr) * DK_ + kc * 64 + gg * 8,
                    &Bt[(w * 32 + i * 8) * 64]);
        }
        __syncthreads();
#pragma unroll
        for (int s = 0; s < 2; ++s) {
            bf16x8 af[4], bb[4];
#pragma unroll
            for (int m = 0; m < 4; ++m) {
                int rl = wr * 64 + m * 16 + lrow;
                af[m] = *reinterpret_cast<const bf16x8*>(
                    &At[rl * 64 + (((s * 4 + lkg) ^ (rl & 7)) * 8)]);
            }
#pragma unroll
            for (int n = 0; n < 4; ++n) {
                int cl = wc * 64 + n * 16 + lrow;
                bb[n] = *reinterpret_cast<const bf16x8*>(
                    &Bt[cl * 64 + (((s * 4 + lkg) ^ (cl & 7)) * 8)]);
            }
#pragma unroll
            for (int m = 0; m < 4; ++m)
#pragma unroll
                for (int n = 0; n < 4; ++n)
                    acc2[m][n] = __builtin_amdgcn_mfma_f32_16x16x32_bf16(
                        af[m], bb[n], acc2[m][n], 0, 0, 0);
        }
        __syncthreads();
    }
#pragma unroll
    for (int m = 0; m < 4; ++m)
#pragma unroll
        for (int n = 0; n < 4; ++n) {
            int colg = c0 + wc * 64 + n * 16 + lrow;
#pragma unroll
            for (int r = 0; r < 4; ++r) {
                int j = wr * 64 + m * 16 + lkg * 4 + r;
                mvb[(size_t)j * D_ + colg] =
                    (acc1[m][n][r] - acc2[m][n][r] * inv2[j]) * mbl[j];
            }
        }
}

// ---------------- Kernel 4c: W_mem_new = W_mem + mk^T @ mvb
__global__ __launch_bounds__(256) void k_wmem(const float* __restrict__ Wmem,
                                              const float* __restrict__ mk_g,
                                              const float* __restrict__ mvb,
                                              float* __restrict__ wout) {
    const int c0 = blockIdx.x * 256;
    const int k0 = blockIdx.y * 8;
    const int tid = threadIdx.x;
    const int tk = tid >> 5, tt = tid & 31;
    float acc[8] = {};
    for (int j = 0; j < NMEM_; ++j) {
        float a = mk_g[(size_t)j * DK_ + k0 + tk];
#pragma unroll
        for (int i = 0; i < 8; ++i)
            acc[i] += a * mvb[(size_t)j * D_ + c0 + tt + 32 * i];
    }
#pragma unroll
    for (int i = 0; i < 8; ++i) {
        size_t off = (size_t)(k0 + tk) * D_ + c0 + tt + 32 * i;
        wout[off] = Wmem[off] + acc[i];
    }
}

// ---------------- Kernel 4d: z_new = z + sum_j nic[j]*mk[j,:]
__global__ void k_znew(const float* __restrict__ z,
                       const float* __restrict__ mk_g,
                       const float* __restrict__ scal,
                       float* __restrict__ zout) {
    int t = threadIdx.x;
    if (t < DK_) {
        float acc = z[t];
        for (int j = 0; j < NMEM_; ++j)
            acc += scal[j * 4 + 1] * mk_g[(size_t)j * DK_ + t];
        zout[t] = acc;
    }
}

extern "C" void kernel_launch(void* const* d_in, const int* in_sizes, int n_in,
                              void* d_out, int out_size, void* d_ws, size_t ws_size,
                              hipStream_t stream) {
    const float* hs   = (const float*)d_in[0];
    const float* Wmq  = (const float*)d_in[1];
    const float* Wmk  = (const float*)d_in[2];
    const float* Wmv  = (const float*)d_in[3];
    const float* Wmbw = (const float*)d_in[4];
    const float* Wmbb = (const float*)d_in[5];
    const float* Wmem = (const float*)d_in[6];
    const float* z    = (const float*)d_in[7];
    float* out  = (float*)d_out;
    float* wout = out + (size_t)S_ * D_;
    float* zout = wout + (size_t)DK_ * D_;

    float* ws = (float*)d_ws;
    float* Q      = ws;                              // 16384*64
    float* denomv = Q + (size_t)S_ * DM_;            // 16384
    float* mk_g   = denomv + S_;                     // 128*384
    float* scal   = mk_g + (size_t)NMEM_ * DK_;      // 512
    float* mvb    = scal + NMEM_ * 4;                // 128*2048
    u16* mq_b  = (u16*)(mvb + (size_t)NMEM_ * D_);   // 16384*384 bf16
    u16* WmT   = mq_b + (size_t)S_ * DK_;            // 2048*384 bf16
    u16* Wmq_b = WmT + (size_t)D_ * DK_;             // 64*2048 bf16
    u16* Wmv_b = Wmq_b + (size_t)DM_ * D_;           // 2048*2048 bf16
    u16* mem_b = Wmv_b + (size_t)D_ * D_;            // 128*2048 bf16
    u16* mk_b  = mem_b + (size_t)NMEM_ * D_;         // 128*384 bf16

    k_convWmq<<<dim3(128), 256, 0, stream>>>(Wmq, Wmq_b);
    k_convWmv<<<dim3(D_ * D_ / 1024), 256, 0, stream>>>(Wmv, Wmv_b);
    k_convWT<<<dim3(D_ / 32, DK_ / 32), 256, 0, stream>>>(Wmem, WmT);
    k_qgemm<<<dim3(S_ / 128), 256, 0, stream>>>(hs, Wmq_b, Q);
    k_dpfp<<<dim3(S_ / 4), 256, 0, stream>>>(Q, z, mq_b, denomv);
    k_main<<<dim3((S_ / 128) * (D_ / 128)), 256, 0, stream>>>(hs, mq_b, WmT, denomv, out);
    k_memb<<<dim3(NMEM_ * D_ / 1024), 256, 0, stream>>>(out, mem_b);
    k_mk<<<dim3(NMEM_), 256, 0, stream>>>(out, Wmk, Wmbw, Wmbb, z, mk_g, mk_b, scal);
    k_mv<<<dim3(D_ / 128), 256, 0, stream>>>(mem_b, Wmv_b, mk_b, WmT, scal, mvb);
    k_wmem<<<dim3(D_ / 256, DK_ / 8), 256, 0, stream>>>(Wmem, mk_g, mvb, wout);
    k_znew<<<dim3(1), 384, 0, stream>>>(z, mk_g, scal, zout);
}

// Round 4
// 206.802 us; speedup vs baseline: 4.1093x; 1.1884x over previous
//
#include <hip/hip_runtime.h>
#include <hip/hip_bf16.h>
#include <math.h>

#define S_ 16384
#define D_ 2048
#define DM_ 64
#define DK_ 384
#define NMEM_ 128
#define EPS_ 1e-5f

typedef __attribute__((ext_vector_type(8))) short bf16x8;
typedef __attribute__((ext_vector_type(4))) float f32x4;
typedef unsigned short u16;

static __device__ __forceinline__ u16 f2bf(float x) {
    __hip_bfloat16 h = __float2bfloat16(x);
    return *reinterpret_cast<u16*>(&h);
}

static __device__ __forceinline__ void gload16(const void* g, void* l) {
    __builtin_amdgcn_global_load_lds(
        (const __attribute__((address_space(1))) unsigned int*)g,
        (__attribute__((address_space(3))) unsigned int*)l, 16, 0, 0);
}

// ---------------- k_prep: all weight conversions in one launch
// blocks [0,4096): Wmv f32->bf16 ; [4096,4224): Wmq ; [4224,4992): W_mem transpose
__global__ __launch_bounds__(256) void k_prep(const float* __restrict__ Wmq,
                                              const float* __restrict__ Wmv,
                                              const float* __restrict__ Wmem,
                                              u16* __restrict__ Wmq_b,
                                              u16* __restrict__ Wmv_b,
                                              u16* __restrict__ WmT) {
    __shared__ float ts[32][33];
    const int bid = blockIdx.x;
    const int tid = threadIdx.x;
    if (bid < 4096) {
        size_t idx = ((size_t)bid * 256 + tid) * 4;
        float4 v = *reinterpret_cast<const float4*>(&Wmv[idx]);
        ushort4 p;
        p.x = f2bf(v.x); p.y = f2bf(v.y); p.z = f2bf(v.z); p.w = f2bf(v.w);
        *reinterpret_cast<ushort4*>(&Wmv_b[idx]) = p;
    } else if (bid < 4224) {
        int idx = ((bid - 4096) * 256 + tid) * 4;
        float4 v = *reinterpret_cast<const float4*>(&Wmq[idx]);
        ushort4 p;
        p.x = f2bf(v.x); p.y = f2bf(v.y); p.z = f2bf(v.z); p.w = f2bf(v.w);
        *reinterpret_cast<ushort4*>(&Wmq_b[idx]) = p;
    } else {
        int t = bid - 4224;
        int c0 = (t & 63) * 32, k0 = (t >> 6) * 32;
        const int tx = tid & 31, ty = tid >> 5;
#pragma unroll
        for (int i = 0; i < 4; ++i)
            ts[ty + 8 * i][tx] = Wmem[(size_t)(k0 + ty + 8 * i) * D_ + c0 + tx];
        __syncthreads();
#pragma unroll
        for (int i = 0; i < 4; ++i)
            WmT[(size_t)(c0 + ty + 8 * i) * DK_ + k0 + tx] = f2bf(ts[tx][ty + 8 * i]);
    }
}

// ---------------- k_qdp: fused Q-GEMM + dpfp + denom
// BM=32, grid 512, 4 waves (2x2): wave = 16 rows x 32 cols
__global__ __launch_bounds__(256) void k_qdp(const float* __restrict__ hs,
                                             const u16* __restrict__ Wmq_b,
                                             const float* __restrict__ z,
                                             u16* __restrict__ mq_b,
                                             float* __restrict__ denomv) {
    __shared__ u16 As[32 * 64];
    __shared__ u16 Bs[64 * 64];
    __shared__ float xs[32][128];
    __shared__ float zs[DK_];
    const int r0 = blockIdx.x * 32;
    const int tid = threadIdx.x;
    const int lane = tid & 63, w = tid >> 6;
    const int lrow = lane & 15, lkg = lane >> 4;
    const int wr = w >> 1, wc = w & 1;
    for (int i = tid; i < DK_; i += 256) zs[i] = z[i];
    f32x4 acc[2];
    const f32x4 zero4 = {0.f, 0.f, 0.f, 0.f};
    acc[0] = zero4; acc[1] = zero4;
    for (int kc = 0; kc < D_ / 64; ++kc) {
#pragma unroll
        for (int i = 0; i < 2; ++i) {
            int flat4 = tid + 256 * i;
            int row = flat4 >> 4, c4 = flat4 & 15;
            const float4 v = *reinterpret_cast<const float4*>(
                &hs[(size_t)(r0 + row) * D_ + kc * 64 + c4 * 4]);
            int off = row * 64 + (((c4 >> 1) ^ (row & 7)) * 8) + (c4 & 1) * 4;
            ushort4 p;
            p.x = f2bf(v.x); p.y = f2bf(v.y); p.z = f2bf(v.z); p.w = f2bf(v.w);
            *reinterpret_cast<ushort4*>(&As[off]) = p;
        }
#pragma unroll
        for (int i = 0; i < 2; ++i) {
            int col = w * 16 + i * 8 + (lane >> 3);
            int gg = (lane & 7) ^ (col & 7);
            gload16(Wmq_b + (size_t)col * D_ + kc * 64 + gg * 8,
                    &Bs[(w * 16 + i * 8) * 64]);
        }
        __syncthreads();
#pragma unroll
        for (int s = 0; s < 2; ++s) {
            int rl = wr * 16 + lrow;
            bf16x8 a_ = *reinterpret_cast<const bf16x8*>(
                &As[rl * 64 + (((s * 4 + lkg) ^ (rl & 7)) * 8)]);
#pragma unroll
            for (int n = 0; n < 2; ++n) {
                int cl = wc * 32 + n * 16 + lrow;
                bf16x8 b_ = *reinterpret_cast<const bf16x8*>(
                    &Bs[cl * 64 + (((s * 4 + lkg) ^ (cl & 7)) * 8)]);
                acc[n] = __builtin_amdgcn_mfma_f32_16x16x32_bf16(a_, b_, acc[n], 0, 0, 0);
            }
        }
        __syncthreads();
    }
    // Q fragments -> xs = [relu(q), relu(-q)]
#pragma unroll
    for (int n = 0; n < 2; ++n) {
        int col = wc * 32 + n * 16 + lrow;
#pragma unroll
        for (int r = 0; r < 4; ++r) {
            int row = wr * 16 + lkg * 4 + r;
            float q = acc[n][r];
            xs[row][col] = fmaxf(q, 0.f);
            xs[row][col + 64] = fmaxf(-q, 0.f);
        }
    }
    __syncthreads();
    // dpfp: 8 threads per row, contiguous 48-chunks
    {
        int row = tid >> 3, sub = tid & 7;
        float pd = 0.f;
#pragma unroll
        for (int t = 0; t < 48; ++t) {
            int m = sub * 48 + t;
            int g = m >> 7, i = m & 127;
            float v = xs[row][i] * xs[row][(i - g - 1) & 127];
            mq_b[(size_t)(r0 + row) * DK_ + m] = f2bf(v);
            pd += zs[m] * v;
        }
        pd += __shfl_down(pd, 4, 8);
        pd += __shfl_down(pd, 2, 8);
        pd += __shfl_down(pd, 1, 8);
        if (sub == 0) denomv[r0 + row] = pd + EPS_;
    }
}

// ---------------- k_main: out = (mq @ WmT^T)/denom + hs, BK=128 (3 K-iters)
__global__ __launch_bounds__(256) void k_main(const float* __restrict__ hs,
                                              const u16* __restrict__ mq_b,
                                              const u16* __restrict__ WmT,
                                              const float* __restrict__ denomv,
                                              float* __restrict__ out) {
    __shared__ u16 At[128 * 128];
    __shared__ u16 Bt[128 * 128];
    __shared__ float dinv[128];
    const int bid = blockIdx.x;
    const int swz = (bid & 7) * 256 + (bid >> 3);   // XCD chunked, 2048 % 8 == 0
    const int r0 = (swz >> 4) * 128, c0 = (swz & 15) * 128;
    const int tid = threadIdx.x;
    const int lane = tid & 63, w = tid >> 6;
    const int lrow = lane & 15, lkg = lane >> 4;
    const int wr = w >> 1, wc = w & 1;
    if (tid < 128) dinv[tid] = 1.f / denomv[r0 + tid];
    f32x4 acc[4][4];
    const f32x4 zero4 = {0.f, 0.f, 0.f, 0.f};
#pragma unroll
    for (int m = 0; m < 4; ++m)
#pragma unroll
        for (int n = 0; n < 4; ++n) acc[m][n] = zero4;
    for (int kc = 0; kc < 3; ++kc) {
        // wave w stages rows w*32..+31; 4 rows per gload16 (row = 256B = 16 granules)
#pragma unroll
        for (int i = 0; i < 8; ++i) {
            int rr = w * 32 + i * 4 + (lane >> 4);
            int gg = (lane & 15) ^ (rr & 7);
            gload16(mq_b + (size_t)(r0 + rr) * DK_ + kc * 128 + gg * 8,
                    &At[(w * 32 + i * 4) * 128]);
            gload16(WmT + (size_t)(c0 + rr) * DK_ + kc * 128 + gg * 8,
                    &Bt[(w * 32 + i * 4) * 128]);
        }
        __syncthreads();
#pragma unroll
        for (int s = 0; s < 4; ++s) {
            bf16x8 af[4], bb[4];
#pragma unroll
            for (int m = 0; m < 4; ++m) {
                int rl = wr * 64 + m * 16 + lrow;
                af[m] = *reinterpret_cast<const bf16x8*>(
                    &At[rl * 128 + (((s * 4 + lkg) ^ (rl & 7)) * 8)]);
            }
#pragma unroll
            for (int n = 0; n < 4; ++n) {
                int cl = wc * 64 + n * 16 + lrow;
                bb[n] = *reinterpret_cast<const bf16x8*>(
                    &Bt[cl * 128 + (((s * 4 + lkg) ^ (cl & 7)) * 8)]);
            }
#pragma unroll
            for (int m = 0; m < 4; ++m)
#pragma unroll
                for (int n = 0; n < 4; ++n)
                    acc[m][n] = __builtin_amdgcn_mfma_f32_16x16x32_bf16(
                        af[m], bb[n], acc[m][n], 0, 0, 0);
        }
        __syncthreads();
    }
#pragma unroll
    for (int m = 0; m < 4; ++m)
#pragma unroll
        for (int n = 0; n < 4; ++n) {
            int colg = c0 + wc * 64 + n * 16 + lrow;
#pragma unroll
            for (int r = 0; r < 4; ++r) {
                int rowl = wr * 64 + m * 16 + lkg * 4 + r;
                size_t off = (size_t)(r0 + rowl) * D_ + colg;
                out[off] = acc[m][n][r] * dinv[rowl] + hs[off];
            }
        }
}

// ---------------- k_mk: per mem-token row: mk, denom2, nic, mb; also mem_b bf16
__global__ __launch_bounds__(256) void k_mk(const float* __restrict__ out,
                                            const float* __restrict__ Wmk,
                                            const float* __restrict__ Wmb_w,
                                            const float* __restrict__ Wmb_b,
                                            const float* __restrict__ z,
                                            float* __restrict__ mk_g,
                                            u16* __restrict__ mk_b,
                                            u16* __restrict__ mem_b,
                                            float* __restrict__ scal) {
    __shared__ float memRow[D_];
    __shared__ float qpart[4][64];
    __shared__ float xv[128];
    __shared__ float mks[DK_];
    __shared__ float red[256];
    const int j = blockIdx.x;
    const int tid = threadIdx.x;
    const float* mem = out + (size_t)(S_ - NMEM_ + j) * D_;
    for (int i = tid; i < D_; i += 256) {
        float v = mem[i];
        memRow[i] = v;
        mem_b[(size_t)j * D_ + i] = f2bf(v);
    }
    __syncthreads();
    {
        int c = tid & 63, seg = tid >> 6;
        float p = 0.f;
        for (int k = seg * 512; k < seg * 512 + 512; ++k)
            p += memRow[k] * Wmk[(size_t)c * D_ + k];
        qpart[seg][c] = p;
    }
    __syncthreads();
    if (tid < 64) {
        float q = qpart[0][tid] + qpart[1][tid] + qpart[2][tid] + qpart[3][tid];
        xv[tid] = fmaxf(q, 0.f);
        xv[tid + 64] = fmaxf(-q, 0.f);
    }
    __syncthreads();
    for (int m = tid; m < DK_; m += 256) {
        int i = m & 127, g = m >> 7;
        float v = xv[i] * xv[(i - g - 1) & 127];
        mks[m] = v;
        mk_g[(size_t)j * DK_ + m] = v;
        mk_b[(size_t)j * DK_ + m] = f2bf(v);
    }
    __syncthreads();
    float pd = 0.f, ps = 0.f;
    for (int m = tid; m < DK_; m += 256) { float v = mks[m]; pd += v * z[m]; ps += v * v; }
    red[tid] = pd; __syncthreads();
    for (int s = 128; s > 0; s >>= 1) { if (tid < s) red[tid] += red[tid + s]; __syncthreads(); }
    float denom2 = red[0] + EPS_;
    __syncthreads();
    red[tid] = ps; __syncthreads();
    for (int s = 128; s > 0; s >>= 1) { if (tid < s) red[tid] += red[tid + s]; __syncthreads(); }
    float mksq = red[0];
    __syncthreads();
    float pb = 0.f;
    for (int k = tid; k < D_; k += 256) pb += memRow[k] * Wmb_w[k];
    red[tid] = pb; __syncthreads();
    for (int s = 128; s > 0; s >>= 1) { if (tid < s) red[tid] += red[tid + s]; __syncthreads(); }
    if (tid == 0) {
        float bsum = red[0] + Wmb_b[0];
        float mb = 1.f / (1.f + expf(-bsum));
        float nic = 1.f - denom2 / (mksq + EPS_);
        nic = fminf(fmaxf(nic, 0.f), 1.f);
        scal[j * 4 + 0] = denom2;
        scal[j * 4 + 1] = nic;
        scal[j * 4 + 2] = mb;
        scal[j * 4 + 3] = mksq;
    }
}

// ---------------- k_mv (MFMA): mvb = (mem@Wmv^T - (mk@W_mem)/denom2)*mb
// BM=128, BN=64 -> grid 32; waves 2x2: wave = 64 rows x 32 cols
__global__ __launch_bounds__(256) void k_mv(const u16* __restrict__ mem_b,
                                            const u16* __restrict__ Wmv_b,
                                            const u16* __restrict__ mk_b,
                                            const u16* __restrict__ WmT,
                                            const float* __restrict__ scal,
                                            float* __restrict__ mvb) {
    __shared__ u16 At[128 * 64];
    __shared__ u16 Bt[64 * 64];
    __shared__ float inv2[128];
    __shared__ float mbl[128];
    const int c0 = blockIdx.x * 64;
    const int tid = threadIdx.x;
    const int lane = tid & 63, w = tid >> 6;
    const int lrow = lane & 15, lkg = lane >> 4;
    const int wr = w >> 1, wc = w & 1;
    if (tid < 128) {
        inv2[tid] = 1.f / scal[tid * 4 + 0];
        mbl[tid] = scal[tid * 4 + 2];
    }
    f32x4 acc1[4][2], acc2[4][2];
    const f32x4 zero4 = {0.f, 0.f, 0.f, 0.f};
#pragma unroll
    for (int m = 0; m < 4; ++m)
#pragma unroll
        for (int n = 0; n < 2; ++n) { acc1[m][n] = zero4; acc2[m][n] = zero4; }
    // ---- loop 1: mem_b @ Wmv_b^T, K = 2048
    for (int kc = 0; kc < D_ / 64; ++kc) {
#pragma unroll
        for (int i = 0; i < 4; ++i) {
            int rr = w * 32 + i * 8 + (lane >> 3);
            int gg = (lane & 7) ^ (rr & 7);
            gload16(mem_b + (size_t)rr * D_ + kc * 64 + gg * 8,
                    &At[(w * 32 + i * 8) * 64]);
        }
#pragma unroll
        for (int i = 0; i < 2; ++i) {
            int cc = w * 16 + i * 8 + (lane >> 3);
            int gg = (lane & 7) ^ (cc & 7);
            gload16(Wmv_b + (size_t)(c0 + cc) * D_ + kc * 64 + gg * 8,
                    &Bt[(w * 16 + i * 8) * 64]);
        }
        __syncthreads();
#pragma unroll
        for (int s = 0; s < 2; ++s) {
            bf16x8 af[4], bb[2];
#pragma unroll
            for (int m = 0; m < 4; ++m) {
                int rl = wr * 64 + m * 16 + lrow;
                af[m] = *reinterpret_cast<const bf16x8*>(
                    &At[rl * 64 + (((s * 4 + lkg) ^ (rl & 7)) * 8)]);
            }
#pragma unroll
            for (int n = 0; n < 2; ++n) {
                int cl = wc * 32 + n * 16 + lrow;
                bb[n] = *reinterpret_cast<const bf16x8*>(
                    &Bt[cl * 64 + (((s * 4 + lkg) ^ (cl & 7)) * 8)]);
            }
#pragma unroll
            for (int m = 0; m < 4; ++m)
#pragma unroll
                for (int n = 0; n < 2; ++n)
                    acc1[m][n] = __builtin_amdgcn_mfma_f32_16x16x32_bf16(
                        af[m], bb[n], acc1[m][n], 0, 0, 0);
        }
        __syncthreads();
    }
    // ---- loop 2: mk_b @ WmT^T, K = 384
    for (int kc = 0; kc < 6; ++kc) {
#pragma unroll
        for (int i = 0; i < 4; ++i) {
            int rr = w * 32 + i * 8 + (lane >> 3);
            int gg = (lane & 7) ^ (rr & 7);
            gload16(mk_b + (size_t)rr * DK_ + kc * 64 + gg * 8,
                    &At[(w * 32 + i * 8) * 64]);
        }
#pragma unroll
        for (int i = 0; i < 2; ++i) {
            int cc = w * 16 + i * 8 + (lane >> 3);
            int gg = (lane & 7) ^ (cc & 7);
            gload16(WmT + (size_t)(c0 + cc) * DK_ + kc * 64 + gg * 8,
                    &Bt[(w * 16 + i * 8) * 64]);
        }
        __syncthreads();
#pragma unroll
        for (int s = 0; s < 2; ++s) {
            bf16x8 af[4], bb[2];
#pragma unroll
            for (int m = 0; m < 4; ++m) {
                int rl = wr * 64 + m * 16 + lrow;
                af[m] = *reinterpret_cast<const bf16x8*>(
                    &At[rl * 64 + (((s * 4 + lkg) ^ (rl & 7)) * 8)]);
            }
#pragma unroll
            for (int n = 0; n < 2; ++n) {
                int cl = wc * 32 + n * 16 + lrow;
                bb[n] = *reinterpret_cast<const bf16x8*>(
                    &Bt[cl * 64 + (((s * 4 + lkg) ^ (cl & 7)) * 8)]);
            }
#pragma unroll
            for (int m = 0; m < 4; ++m)
#pragma unroll
                for (int n = 0; n < 2; ++n)
                    acc2[m][n] = __builtin_amdgcn_mfma_f32_16x16x32_bf16(
                        af[m], bb[n], acc2[m][n], 0, 0, 0);
        }
        __syncthreads();
    }
#pragma unroll
    for (int m = 0; m < 4; ++m)
#pragma unroll
        for (int n = 0; n < 2; ++n) {
            int colg = c0 + wc * 32 + n * 16 + lrow;
#pragma unroll
            for (int r = 0; r < 4; ++r) {
                int j = wr * 64 + m * 16 + lkg * 4 + r;
                mvb[(size_t)j * D_ + colg] =
                    (acc1[m][n][r] - acc2[m][n][r] * inv2[j]) * mbl[j];
            }
        }
}

// ---------------- k_wmem: W_mem_new = W_mem + mk^T @ mvb ; y==48 does z_new
__global__ __launch_bounds__(256) void k_wmem(const float* __restrict__ Wmem,
                                              const float* __restrict__ mk_g,
                                              const float* __restrict__ mvb,
                                              const float* __restrict__ scal,
                                              const float* __restrict__ z,
                                              float* __restrict__ wout,
                                              float* __restrict__ zout) {
    const int tid = threadIdx.x;
    if (blockIdx.y == 48) {
        if (blockIdx.x == 0) {
            for (int t = tid; t < DK_; t += 256) {
                float acc = z[t];
                for (int j = 0; j < NMEM_; ++j)
                    acc += scal[j * 4 + 1] * mk_g[(size_t)j * DK_ + t];
                zout[t] = acc;
            }
        }
        return;
    }
    const int c0 = blockIdx.x * 256;
    const int k0 = blockIdx.y * 8;
    const int tk = tid >> 5, tt = tid & 31;
    float acc[8] = {};
    for (int j = 0; j < NMEM_; ++j) {
        float a = mk_g[(size_t)j * DK_ + k0 + tk];
#pragma unroll
        for (int i = 0; i < 8; ++i)
            acc[i] += a * mvb[(size_t)j * D_ + c0 + tt + 32 * i];
    }
#pragma unroll
    for (int i = 0; i < 8; ++i) {
        size_t off = (size_t)(k0 + tk) * D_ + c0 + tt + 32 * i;
        wout[off] = Wmem[off] + acc[i];
    }
}

extern "C" void kernel_launch(void* const* d_in, const int* in_sizes, int n_in,
                              void* d_out, int out_size, void* d_ws, size_t ws_size,
                              hipStream_t stream) {
    const float* hs   = (const float*)d_in[0];
    const float* Wmq  = (const float*)d_in[1];
    const float* Wmk  = (const float*)d_in[2];
    const float* Wmv  = (const float*)d_in[3];
    const float* Wmbw = (const float*)d_in[4];
    const float* Wmbb = (const float*)d_in[5];
    const float* Wmem = (const float*)d_in[6];
    const float* z    = (const float*)d_in[7];
    float* out  = (float*)d_out;
    float* wout = out + (size_t)S_ * D_;
    float* zout = wout + (size_t)DK_ * D_;

    float* ws = (float*)d_ws;
    float* denomv = ws;                              // 16384
    float* mk_g   = denomv + S_;                     // 128*384
    float* scal   = mk_g + (size_t)NMEM_ * DK_;      // 512
    float* mvb    = scal + NMEM_ * 4;                // 128*2048
    u16* mq_b  = (u16*)(mvb + (size_t)NMEM_ * D_);   // 16384*384 bf16
    u16* WmT   = mq_b + (size_t)S_ * DK_;            // 2048*384 bf16
    u16* Wmq_b = WmT + (size_t)D_ * DK_;             // 64*2048 bf16
    u16* Wmv_b = Wmq_b + (size_t)DM_ * D_;           // 2048*2048 bf16
    u16* mem_b = Wmv_b + (size_t)D_ * D_;            // 128*2048 bf16
    u16* mk_b  = mem_b + (size_t)NMEM_ * D_;         // 128*384 bf16

    k_prep<<<dim3(4992), 256, 0, stream>>>(Wmq, Wmv, Wmem, Wmq_b, Wmv_b, WmT);
    k_qdp<<<dim3(S_ / 32), 256, 0, stream>>>(hs, Wmq_b, z, mq_b, denomv);
    k_main<<<dim3((S_ / 128) * (D_ / 128)), 256, 0, stream>>>(hs, mq_b, WmT, denomv, out);
    k_mk<<<dim3(NMEM_), 256, 0, stream>>>(out, Wmk, Wmbw, Wmbb, z, mk_g, mk_b, mem_b, scal);
    k_mv<<<dim3(D_ / 64), 256, 0, stream>>>(mem_b, Wmv_b, mk_b, WmT, scal, mvb);
    k_wmem<<<dim3(D_ / 256, DK_ / 8 + 1), 256, 0, stream>>>(Wmem, mk_g, mvb, scal, z, wout, zout);
}